// Round 1
// baseline (353.887 us; speedup 1.0000x reference)
//
#include <hip/hip_runtime.h>
#include <math.h>

#define T_DIM   8
#define N_TOK   16384
#define C_DIM   64
#define K_TOT   (T_DIM * N_TOK)   // 131072 reduction rows per batch
#define N_BATCH 4

// ---------------------------------------------------------------------------
// K1: partial kv accumulation. grid = 4*bpb blocks, 256 threads (4 waves).
// Each wave owns the full 64x64 tile via an 8x8 per-lane register tile and
// streams a strided slice of the K dimension. 4 waves reduce via LDS, block
// writes one 64x64 fp32 partial tile to ws.
// ---------------------------------------------------------------------------
__global__ __launch_bounds__(256, 2) void k1_accum(
    const float* __restrict__ key, const float* __restrict__ val,
    float* __restrict__ part, int bpb) {
  int blk  = blockIdx.x;
  int b    = blk / bpb;          // batch
  int p    = blk % bpb;          // block within batch
  int wave = threadIdx.x >> 6;
  int lane = threadIdx.x & 63;
  int i = lane >> 3;             // c-octet  (rows 8i..8i+7 of kv tile)
  int j = lane & 7;              // d-octet  (cols 8j..8j+7)

  int wpb   = bpb * 4;           // waves per batch
  int q     = p * 4 + wave;      // wave index within batch
  int steps = K_TOT / wpb;

  float acc[8][8];
#pragma unroll
  for (int a = 0; a < 8; a++)
#pragma unroll
    for (int c = 0; c < 8; c++) acc[a][c] = 0.f;

  const float4* k4 = (const float4*)key;
  const float4* v4 = (const float4*)val;
  size_t base_row = (size_t)b * K_TOT;

  int k = q;
#pragma unroll 2
  for (int s = 0; s < steps; s++, k += wpb) {
    size_t row = (base_row + (size_t)k) * 16;  // row start in float4 units
    float4 ka = k4[row + 2 * i];
    float4 kb = k4[row + 2 * i + 1];
    float4 va = v4[row + 2 * j];
    float4 vb = v4[row + 2 * j + 1];
    float kr[8] = {ka.x, ka.y, ka.z, ka.w, kb.x, kb.y, kb.z, kb.w};
    float vr[8] = {va.x, va.y, va.z, va.w, vb.x, vb.y, vb.z, vb.w};
#pragma unroll
    for (int a = 0; a < 8; a++)
#pragma unroll
      for (int c = 0; c < 8; c++)
        acc[a][c] = fmaf(kr[a], vr[c], acc[a][c]);
  }

  // block reduce: 4 wave tiles -> 1 tile, via 64 KiB LDS
  __shared__ float red[4][4096];
#pragma unroll
  for (int a = 0; a < 8; a++) {
    int c = 8 * i + a;
    *(float4*)&red[wave][c * 64 + 8 * j] =
        make_float4(acc[a][0], acc[a][1], acc[a][2], acc[a][3]);
    *(float4*)&red[wave][c * 64 + 8 * j + 4] =
        make_float4(acc[a][4], acc[a][5], acc[a][6], acc[a][7]);
  }
  __syncthreads();

  int t = threadIdx.x;
  float* dst = part + (size_t)blk * 4096;
#pragma unroll
  for (int x = 0; x < 16; x++) {
    int e = t + 256 * x;  // stride-256: conflict-free LDS reads, coalesced store
    dst[e] = red[0][e] + red[1][e] + red[2][e] + red[3][e];
  }
}

// ---------------------------------------------------------------------------
// K2: reduce bpb partial tiles per batch -> kv[b][c][d].
// grid = 256 blocks (b*64 + c), 256 threads = 4 p-slices x 64 d.
// ---------------------------------------------------------------------------
__global__ __launch_bounds__(256, 4) void k2_reduce(
    const float* __restrict__ part, float* __restrict__ kv, int bpb) {
  int b  = blockIdx.x >> 6;
  int c  = blockIdx.x & 63;
  int p4 = threadIdx.x >> 6;
  int d  = threadIdx.x & 63;

  float s = 0.f;
  int iters = bpb >> 2;
  const float* src = part + (size_t)(b * bpb) * 4096 + c * 64 + d;
#pragma unroll 4
  for (int x = 0; x < iters; x++) s += src[(size_t)(p4 + 4 * x) * 4096];

  __shared__ float l[256];
  l[threadIdx.x] = s;
  __syncthreads();
  if (p4 == 0)
    kv[((size_t)b * 64 + c) * 64 + d] = l[d] + l[64 + d] + l[128 + d] + l[192 + d];
}

// ---------------------------------------------------------------------------
// K3: softmax over C (fused preamble, per-block redundant but L2-hot) then
// out[b,m,d] = alpha * sum_c key_cur[b,m,c]*P[c,d] + val_cur[b,m,d].
// grid = 4*256 blocks, 64 threads; 8x8 per-lane register tile over a
// 64(m) x 64(d) block tile; key staged transposed in LDS (stride 68:
// 16B-aligned b128 reads, <=2-way bank aliasing).
// ---------------------------------------------------------------------------
__global__ __launch_bounds__(64, 4) void k3_out(
    const float* __restrict__ kv, const float* __restrict__ keyc,
    const float* __restrict__ valc, const float* __restrict__ alphap,
    float* __restrict__ out) {
  __shared__ float kT[64 * 68];   // kT[c][m], stride 68
  __shared__ float P[64 * 64];    // P[c][d]

  int bb = blockIdx.x >> 8;
  int mb = blockIdx.x & 255;
  int m0 = mb * 64;
  int lane = threadIdx.x;  // 0..63
  int i = lane >> 3;       // m-octet
  int j = lane & 7;        // d-octet

  // --- softmax over c for column d = lane (one global pass, rest in LDS) ---
  const float* kvb = kv + (size_t)bb * 4096;
  float mx = -3.4e38f;
  for (int c = 0; c < 64; c++) {
    float v = kvb[c * 64 + lane];  // coalesced 256B per c
    P[c * 64 + lane] = v;
    mx = fmaxf(mx, v);
  }
  float sum = 0.f;
  for (int c = 0; c < 64; c++) {
    float e = __expf(P[c * 64 + lane] - mx);
    P[c * 64 + lane] = e;
    sum += e;
  }
  float inv = 1.f / sum;
  for (int c = 0; c < 64; c++) P[c * 64 + lane] *= inv;

  // --- stage key_cur block transposed: kT[c][m] ---
  const float* kbp = keyc + ((size_t)bb * N_TOK + m0) * 64;
#pragma unroll 4
  for (int r = 0; r < 64; r++) kT[lane * 68 + r] = kbp[(size_t)r * 64 + lane];
  __syncthreads();

  // --- 64x64 tile GEMM, 8x8 per lane ---
  float acc[8][8];
#pragma unroll
  for (int a = 0; a < 8; a++)
#pragma unroll
    for (int d = 0; d < 8; d++) acc[a][d] = 0.f;

  for (int c = 0; c < 64; c++) {
    float4 a0 = *(const float4*)&kT[c * 68 + 8 * i];
    float4 a1 = *(const float4*)&kT[c * 68 + 8 * i + 4];
    float4 p0 = *(const float4*)&P[c * 64 + 8 * j];
    float4 p1 = *(const float4*)&P[c * 64 + 8 * j + 4];
    float ar[8] = {a0.x, a0.y, a0.z, a0.w, a1.x, a1.y, a1.z, a1.w};
    float pr[8] = {p0.x, p0.y, p0.z, p0.w, p1.x, p1.y, p1.z, p1.w};
#pragma unroll
    for (int a = 0; a < 8; a++)
#pragma unroll
      for (int d = 0; d < 8; d++)
        acc[a][d] = fmaf(ar[a], pr[d], acc[a][d]);
  }

  // --- epilogue: out = alpha*acc + val_cur ---
  float alpha = alphap[0];
  size_t ob = ((size_t)bb * N_TOK + m0) * 64;
#pragma unroll
  for (int a = 0; a < 8; a++) {
    int m = 8 * i + a;
    size_t off = ob + (size_t)m * 64 + 8 * j;
    float4 v0 = *(const float4*)&valc[off];
    float4 v1 = *(const float4*)&valc[off + 4];
    float4 o0 = make_float4(fmaf(alpha, acc[a][0], v0.x),
                            fmaf(alpha, acc[a][1], v0.y),
                            fmaf(alpha, acc[a][2], v0.z),
                            fmaf(alpha, acc[a][3], v0.w));
    float4 o1 = make_float4(fmaf(alpha, acc[a][4], v1.x),
                            fmaf(alpha, acc[a][5], v1.y),
                            fmaf(alpha, acc[a][6], v1.z),
                            fmaf(alpha, acc[a][7], v1.w));
    *(float4*)&out[off] = o0;
    *(float4*)&out[off + 4] = o1;
  }
}

// ---------------------------------------------------------------------------
extern "C" void kernel_launch(void* const* d_in, const int* in_sizes, int n_in,
                              void* d_out, int out_size, void* d_ws,
                              size_t ws_size, hipStream_t stream) {
  const float* key_mem = (const float*)d_in[0];
  const float* val_mem = (const float*)d_in[1];
  const float* key_cur = (const float*)d_in[2];
  const float* val_cur = (const float*)d_in[3];
  const float* alpha   = (const float*)d_in[4];
  float* out = (float*)d_out;
  float* ws  = (float*)d_ws;

  // adaptive partial-tile count vs workspace size (128 -> 32 -> 8 blocks/batch)
  int bpb = 128;
  while (bpb > 8 &&
         ((size_t)(4 * bpb) * 4096 + 4096 * N_BATCH) * sizeof(float) > ws_size)
    bpb >>= 2;

  float* part = ws;
  float* kv   = ws + (size_t)(4 * bpb) * 4096;

  k1_accum<<<4 * bpb, 256, 0, stream>>>(key_mem, val_mem, part, bpb);
  k2_reduce<<<256, 256, 0, stream>>>(part, kv, bpb);
  k3_out<<<N_BATCH * (N_TOK / 64), 64, 0, stream>>>(kv, key_cur, val_cur, alpha,
                                                    out);
}

// Round 2
// 345.609 us; speedup vs baseline: 1.0240x; 1.0240x over previous
//
#include <hip/hip_runtime.h>
#include <math.h>

#define T_DIM   8
#define N_TOK   16384
#define C_DIM   64
#define K_TOT   (T_DIM * N_TOK)   // 131072 reduction rows per batch
#define N_BATCH 4

// ---------------------------------------------------------------------------
// K1: partial kv accumulation. grid = 4*bpb blocks, 512 threads (8 waves).
// Each wave owns the full 64x64 fp32 tile via an 8x8 per-lane register tile
// and streams a strided slice of K with register-rotation prefetch.
// 8 waves reduce through a 32 KiB 2-buffer LDS scheme; block writes one
// 64x64 partial tile. 2 blocks/CU x 8 waves = 16 waves/CU.
// ---------------------------------------------------------------------------
__global__ __launch_bounds__(512, 4) void k1_accum(
    const float* __restrict__ key, const float* __restrict__ val,
    float* __restrict__ part, int bpb) {
  int blk  = blockIdx.x;
  int b    = blk / bpb;
  int p    = blk % bpb;
  int wave = threadIdx.x >> 6;
  int lane = threadIdx.x & 63;
  int i = lane >> 3;             // c-octet (key channel octet)
  int j = lane & 7;              // d-octet (val channel octet)

  int wpb   = bpb * 8;           // waves per batch
  int q     = p * 8 + wave;      // this wave's index within batch
  int steps = K_TOT / wpb;

  float acc[8][8];
#pragma unroll
  for (int a = 0; a < 8; a++)
#pragma unroll
    for (int c = 0; c < 8; c++) acc[a][c] = 0.f;

  const float4* k4 = (const float4*)key;
  const float4* v4 = (const float4*)val;
  size_t base = (size_t)b * K_TOT;

  // rotation prefetch: loads for row s+1 issue before FMAs of row s
  size_t row = (base + (size_t)q) * 16;
  float4 ka = k4[row + 2 * i];
  float4 kb = k4[row + 2 * i + 1];
  float4 va = v4[row + 2 * j];
  float4 vb = v4[row + 2 * j + 1];

  int k = q + wpb;
#pragma unroll 2
  for (int s = 0; s < steps - 1; s++, k += wpb) {
    size_t r2 = (base + (size_t)k) * 16;
    float4 nka = k4[r2 + 2 * i];
    float4 nkb = k4[r2 + 2 * i + 1];
    float4 nva = v4[r2 + 2 * j];
    float4 nvb = v4[r2 + 2 * j + 1];
    {
      float kr[8] = {ka.x, ka.y, ka.z, ka.w, kb.x, kb.y, kb.z, kb.w};
      float vr[8] = {va.x, va.y, va.z, va.w, vb.x, vb.y, vb.z, vb.w};
#pragma unroll
      for (int a = 0; a < 8; a++)
#pragma unroll
        for (int c = 0; c < 8; c++)
          acc[a][c] = fmaf(kr[a], vr[c], acc[a][c]);
    }
    ka = nka; kb = nkb; va = nva; vb = nvb;
  }
  {
    float kr[8] = {ka.x, ka.y, ka.z, ka.w, kb.x, kb.y, kb.z, kb.w};
    float vr[8] = {va.x, va.y, va.z, va.w, vb.x, vb.y, vb.z, vb.w};
#pragma unroll
    for (int a = 0; a < 8; a++)
#pragma unroll
      for (int c = 0; c < 8; c++)
        acc[a][c] = fmaf(kr[a], vr[c], acc[a][c]);
  }

  // --- 8-wave reduce via 2 LDS buffers (32 KiB) ---
  __shared__ float red[2][4096];
  if (wave < 2) {
#pragma unroll
    for (int a = 0; a < 8; a++) {
      int c = 8 * i + a;
      *(float4*)&red[wave][c * 64 + 8 * j] =
          make_float4(acc[a][0], acc[a][1], acc[a][2], acc[a][3]);
      *(float4*)&red[wave][c * 64 + 8 * j + 4] =
          make_float4(acc[a][4], acc[a][5], acc[a][6], acc[a][7]);
    }
  }
  __syncthreads();
#pragma unroll
  for (int g = 1; g < 4; g++) {
    if (wave >= 2 * g && wave < 2 * g + 2) {
      int wb = wave - 2 * g;
#pragma unroll
      for (int a = 0; a < 8; a++) {
        int c = 8 * i + a;
        float4* d0 = (float4*)&red[wb][c * 64 + 8 * j];
        float4* d1 = (float4*)&red[wb][c * 64 + 8 * j + 4];
        float4 x0 = *d0, x1 = *d1;
        *d0 = make_float4(x0.x + acc[a][0], x0.y + acc[a][1],
                          x0.z + acc[a][2], x0.w + acc[a][3]);
        *d1 = make_float4(x1.x + acc[a][4], x1.y + acc[a][5],
                          x1.z + acc[a][6], x1.w + acc[a][7]);
      }
    }
    __syncthreads();
  }

  float* dst = part + (size_t)blk * 4096;
  int t = threadIdx.x;
#pragma unroll
  for (int x = 0; x < 8; x++) {
    int e = t + 512 * x;
    dst[e] = red[0][e] + red[1][e];
  }
}

// ---------------------------------------------------------------------------
// K2: reduce bpb partial tiles per batch -> kv[b][c][d].
// grid = 256 blocks (b*64 + c), 256 threads = 4 p-slices x 64 d.
// ---------------------------------------------------------------------------
__global__ __launch_bounds__(256, 4) void k2_reduce(
    const float* __restrict__ part, float* __restrict__ kv, int bpb) {
  int b  = blockIdx.x >> 6;
  int c  = blockIdx.x & 63;
  int p4 = threadIdx.x >> 6;
  int d  = threadIdx.x & 63;

  float s = 0.f;
  int iters = bpb >> 2;
  const float* src = part + (size_t)(b * bpb) * 4096 + c * 64 + d;
#pragma unroll 4
  for (int x = 0; x < iters; x++) s += src[(size_t)(p4 + 4 * x) * 4096];

  __shared__ float l[256];
  l[threadIdx.x] = s;
  __syncthreads();
  if (p4 == 0)
    kv[((size_t)b * 64 + c) * 64 + d] = l[d] + l[64 + d] + l[128 + d] + l[192 + d];
}

// ---------------------------------------------------------------------------
// K2b: softmax over C (axis=1) -> P[b][c][d]. grid = 4 blocks, 64 threads.
// Each thread owns one d column, 64 c values register-resident.
// ---------------------------------------------------------------------------
__global__ __launch_bounds__(64, 1) void k2b_softmax(
    const float* __restrict__ kv, float* __restrict__ P) {
  int b = blockIdx.x;
  int d = threadIdx.x;
  const float* s = kv + (size_t)b * 4096 + d;
  float v[64];
#pragma unroll
  for (int c = 0; c < 64; c++) v[c] = s[c * 64];  // independent, pipelined
  float mx = v[0];
#pragma unroll
  for (int c = 1; c < 64; c++) mx = fmaxf(mx, v[c]);
  float sum = 0.f;
#pragma unroll
  for (int c = 0; c < 64; c++) {
    v[c] = __expf(v[c] - mx);
    sum += v[c];
  }
  float inv = 1.f / sum;
  float* o = P + (size_t)b * 4096 + d;
#pragma unroll
  for (int c = 0; c < 64; c++) o[c * 64] = v[c] * inv;
}

// ---------------------------------------------------------------------------
// K3: out[b,m,d] = alpha * sum_c key_cur[b,m,c]*P[c,d] + val_cur[b,m,d].
// grid = 4*256 blocks, 256 threads (4 waves). 64(m)x64(d) tile per block;
// P (16 KiB) + transposed key (17 KiB) in LDS -> 4 blocks/CU, 16 waves/CU.
// Per lane: 2(m) x 8(d) register tile.
// ---------------------------------------------------------------------------
__global__ __launch_bounds__(256, 4) void k3_out(
    const float* __restrict__ P, const float* __restrict__ keyc,
    const float* __restrict__ valc, const float* __restrict__ alphap,
    float* __restrict__ out) {
  __shared__ float Ps[4096];      // P[c][d]
  __shared__ float kT[64 * 68];   // kT[c][m], stride 68 (8B-aligned b64 reads)

  int bb = blockIdx.x >> 8;
  int mb = blockIdx.x & 255;
  int m0 = mb * 64;
  int t = threadIdx.x;

  // cooperative load of P (coalesced float4)
  const float4* p4 = (const float4*)(P + (size_t)bb * 4096);
  float4* ps4 = (float4*)Ps;
#pragma unroll
  for (int u = 0; u < 4; u++) ps4[t + 256 * u] = p4[t + 256 * u];

  // cooperative transposed staging of key block: thread -> (row r, c-chunk)
  int r  = t >> 2;
  int cb = (t & 3) * 16;
  const float* krow = keyc + ((size_t)bb * N_TOK + m0 + r) * 64;
#pragma unroll
  for (int u = 0; u < 4; u++) {
    float4 kk = *(const float4*)&krow[cb + 4 * u];
    int c = cb + 4 * u;
    kT[(c + 0) * 68 + r] = kk.x;
    kT[(c + 1) * 68 + r] = kk.y;
    kT[(c + 2) * 68 + r] = kk.z;
    kT[(c + 3) * 68 + r] = kk.w;
  }
  __syncthreads();

  int wave = t >> 6, lane = t & 63;
  int mi = lane >> 3, j = lane & 7;
  int m = wave * 16 + mi * 2;     // 2 consecutive m rows per lane

  float acc[2][8];
#pragma unroll
  for (int a = 0; a < 2; a++)
#pragma unroll
    for (int d = 0; d < 8; d++) acc[a][d] = 0.f;

#pragma unroll 4
  for (int c = 0; c < 64; c++) {
    float2 kk = *(const float2*)&kT[c * 68 + m];
    float4 p0 = *(const float4*)&Ps[c * 64 + 8 * j];
    float4 p1 = *(const float4*)&Ps[c * 64 + 8 * j + 4];
    float pr[8] = {p0.x, p0.y, p0.z, p0.w, p1.x, p1.y, p1.z, p1.w};
#pragma unroll
    for (int d = 0; d < 8; d++) {
      acc[0][d] = fmaf(kk.x, pr[d], acc[0][d]);
      acc[1][d] = fmaf(kk.y, pr[d], acc[1][d]);
    }
  }

  float alpha = alphap[0];
#pragma unroll
  for (int a = 0; a < 2; a++) {
    size_t off = ((size_t)bb * N_TOK + m0 + m + a) * 64 + 8 * j;
    float4 v0 = *(const float4*)&valc[off];
    float4 v1 = *(const float4*)&valc[off + 4];
    float4 o0 = make_float4(fmaf(alpha, acc[a][0], v0.x),
                            fmaf(alpha, acc[a][1], v0.y),
                            fmaf(alpha, acc[a][2], v0.z),
                            fmaf(alpha, acc[a][3], v0.w));
    float4 o1 = make_float4(fmaf(alpha, acc[a][4], v1.x),
                            fmaf(alpha, acc[a][5], v1.y),
                            fmaf(alpha, acc[a][6], v1.z),
                            fmaf(alpha, acc[a][7], v1.w));
    *(float4*)&out[off] = o0;
    *(float4*)&out[off + 4] = o1;
  }
}

// ---------------------------------------------------------------------------
extern "C" void kernel_launch(void* const* d_in, const int* in_sizes, int n_in,
                              void* d_out, int out_size, void* d_ws,
                              size_t ws_size, hipStream_t stream) {
  const float* key_mem = (const float*)d_in[0];
  const float* val_mem = (const float*)d_in[1];
  const float* key_cur = (const float*)d_in[2];
  const float* val_cur = (const float*)d_in[3];
  const float* alpha   = (const float*)d_in[4];
  float* out = (float*)d_out;
  float* ws  = (float*)d_ws;

  // partial tiles: one 64x64 tile per block; P aliases the consumed part area
  int bpb = 128;
  while (bpb > 8 &&
         ((size_t)(N_BATCH * bpb) * 4096 + 4096 * N_BATCH) * sizeof(float) >
             ws_size)
    bpb >>= 1;

  float* part = ws;                                   // 4*bpb tiles
  float* kv   = ws + (size_t)(N_BATCH * bpb) * 4096;  // 4 tiles
  float* P    = ws;                                   // aliases part (consumed)

  k1_accum<<<N_BATCH * bpb, 512, 0, stream>>>(key_mem, val_mem, part, bpb);
  k2_reduce<<<256, 256, 0, stream>>>(part, kv, bpb);
  k2b_softmax<<<N_BATCH, 64, 0, stream>>>(kv, P);
  k3_out<<<N_BATCH * (N_TOK / 64), 256, 0, stream>>>(P, key_cur, val_cur,
                                                     alpha, out);
}

// Round 3
// 343.149 us; speedup vs baseline: 1.0313x; 1.0072x over previous
//
#include <hip/hip_runtime.h>
#include <math.h>

#define N_TOK   16384
#define K_TOT   (8 * N_TOK)      // 131072 reduction rows per batch
#define N_BATCH 4
#define BPB     128              // K1 blocks per batch
#define RPB     (K_TOT / BPB)    // 1024 contiguous rows per block
#define BK      64               // rows per staging buffer
#define NBUF    (RPB / BK)       // 16 buffers

typedef const __attribute__((address_space(1))) unsigned int* as1_u32p;
typedef __attribute__((address_space(3))) unsigned int* as3_u32p;

// async 16B/lane global->LDS: gptr per-lane, lptr wave-uniform base (HW adds lane*16)
__device__ __forceinline__ void gload16(const float* g, float* l) {
  __builtin_amdgcn_global_load_lds((as1_u32p)g, (as3_u32p)l, 16, 0, 0);
}

// ---------------------------------------------------------------------------
// K1: partial kv accumulation. grid = 512 blocks x 512 thr (8 waves).
// Each block owns 1024 CONTIGUOUS rows; double-buffered LDS staging via
// global_load_lds (1 KiB distinct bytes per vmem instr — kills the 8-fold
// address-duplication instruction-rate bottleneck). Each wave computes the
// full 64x64 fp32 tile (8x8/lane) over its 8 rows per buffer from LDS
// (broadcast reads, <=2-way banks = free). 8-wave LDS reduce at the end.
// ---------------------------------------------------------------------------
__global__ __launch_bounds__(512, 4) void k1_accum(
    const float* __restrict__ key, const float* __restrict__ val,
    float* __restrict__ part) {
  __shared__ float lds[16384];   // [2 bufs][key 4096 | val 4096] = 64 KiB
  int blk  = blockIdx.x;
  int b    = blk / BPB;
  int p    = blk % BPB;
  int wave = threadIdx.x >> 6;
  int lane = threadIdx.x & 63;
  int i = lane >> 3;             // c-octet
  int j = lane & 7;              // d-octet

  size_t row0 = (size_t)b * K_TOT + (size_t)p * RPB;
  const float* kb = key + row0 * 64;
  const float* vb = val + row0 * 64;

  float acc[8][8];
#pragma unroll
  for (int a = 0; a < 8; a++)
#pragma unroll
    for (int c = 0; c < 8; c++) acc[a][c] = 0.f;

  // stage buffer: key BK*64 floats then val BK*64 floats; 256-float chunks,
  // wave w stages chunks w and w+8 of each array (lptr wave-uniform).
  auto stage = [&](int t, int buf) {
    const float* kg = kb + (size_t)t * (BK * 64);
    const float* vg = vb + (size_t)t * (BK * 64);
    float* dl = &lds[buf * 8192];
    gload16(kg + wave * 256 + lane * 4,        dl + wave * 256);
    gload16(kg + (wave + 8) * 256 + lane * 4,  dl + (wave + 8) * 256);
    gload16(vg + wave * 256 + lane * 4,        dl + 4096 + wave * 256);
    gload16(vg + (wave + 8) * 256 + lane * 4,  dl + 4096 + (wave + 8) * 256);
  };

  stage(0, 0);
  for (int t = 0; t < NBUF; t++) {
    __syncthreads();                       // staging of buf (t&1) complete
    if (t + 1 < NBUF) stage(t + 1, (t + 1) & 1);
    const float* ks = &lds[(t & 1) * 8192];
    const float* vs = ks + 4096;
#pragma unroll
    for (int rr = 0; rr < BK / 8; rr++) {
      int r = wave + rr * 8;               // each row consumed by ONE wave
      float4 k0 = *(const float4*)&ks[r * 64 + 8 * i];
      float4 k1 = *(const float4*)&ks[r * 64 + 8 * i + 4];
      float4 v0 = *(const float4*)&vs[r * 64 + 8 * j];
      float4 v1 = *(const float4*)&vs[r * 64 + 8 * j + 4];
      float kr[8] = {k0.x, k0.y, k0.z, k0.w, k1.x, k1.y, k1.z, k1.w};
      float vr[8] = {v0.x, v0.y, v0.z, v0.w, v1.x, v1.y, v1.z, v1.w};
#pragma unroll
      for (int a = 0; a < 8; a++)
#pragma unroll
        for (int c = 0; c < 8; c++)
          acc[a][c] = fmaf(kr[a], vr[c], acc[a][c]);
    }
  }

  // --- 8-wave reduce, aliasing lds[0..8192) (last compute used lds[8192..)) ---
  float (*red)[4096] = (float(*)[4096])lds;
  if (wave < 2) {
#pragma unroll
    for (int a = 0; a < 8; a++) {
      int c = 8 * i + a;
      *(float4*)&red[wave][c * 64 + 8 * j] =
          make_float4(acc[a][0], acc[a][1], acc[a][2], acc[a][3]);
      *(float4*)&red[wave][c * 64 + 8 * j + 4] =
          make_float4(acc[a][4], acc[a][5], acc[a][6], acc[a][7]);
    }
  }
  __syncthreads();
#pragma unroll
  for (int g = 1; g < 4; g++) {
    if (wave >= 2 * g && wave < 2 * g + 2) {
      int wb = wave - 2 * g;
#pragma unroll
      for (int a = 0; a < 8; a++) {
        int c = 8 * i + a;
        float4* d0 = (float4*)&red[wb][c * 64 + 8 * j];
        float4* d1 = (float4*)&red[wb][c * 64 + 8 * j + 4];
        float4 x0 = *d0, x1 = *d1;
        *d0 = make_float4(x0.x + acc[a][0], x0.y + acc[a][1],
                          x0.z + acc[a][2], x0.w + acc[a][3]);
        *d1 = make_float4(x1.x + acc[a][4], x1.y + acc[a][5],
                          x1.z + acc[a][6], x1.w + acc[a][7]);
      }
    }
    __syncthreads();
  }

  float* dst = part + (size_t)blk * 4096;
  int t = threadIdx.x;
#pragma unroll
  for (int x = 0; x < 8; x++) {
    int e = t + 512 * x;
    dst[e] = red[0][e] + red[1][e];
  }
}

// ---------------------------------------------------------------------------
// K2: reduce bpb partial tiles per batch -> kv[b][c][d].
// ---------------------------------------------------------------------------
__global__ __launch_bounds__(256, 4) void k2_reduce(
    const float* __restrict__ part, float* __restrict__ kv, int bpb) {
  int b  = blockIdx.x >> 6;
  int c  = blockIdx.x & 63;
  int p4 = threadIdx.x >> 6;
  int d  = threadIdx.x & 63;

  float s = 0.f;
  int iters = bpb >> 2;
  const float* src = part + (size_t)(b * bpb) * 4096 + c * 64 + d;
#pragma unroll 4
  for (int x = 0; x < iters; x++) s += src[(size_t)(p4 + 4 * x) * 4096];

  __shared__ float l[256];
  l[threadIdx.x] = s;
  __syncthreads();
  if (p4 == 0)
    kv[((size_t)b * 64 + c) * 64 + d] = l[d] + l[64 + d] + l[128 + d] + l[192 + d];
}

// ---------------------------------------------------------------------------
// K2b: softmax over C (axis=1) -> P[b][c][d]. grid = 4 blocks, 64 threads.
// ---------------------------------------------------------------------------
__global__ __launch_bounds__(64, 1) void k2b_softmax(
    const float* __restrict__ kv, float* __restrict__ P) {
  int b = blockIdx.x;
  int d = threadIdx.x;
  const float* s = kv + (size_t)b * 4096 + d;
  float v[64];
#pragma unroll
  for (int c = 0; c < 64; c++) v[c] = s[c * 64];
  float mx = v[0];
#pragma unroll
  for (int c = 1; c < 64; c++) mx = fmaxf(mx, v[c]);
  float sum = 0.f;
#pragma unroll
  for (int c = 0; c < 64; c++) {
    v[c] = __expf(v[c] - mx);
    sum += v[c];
  }
  float inv = 1.f / sum;
  float* o = P + (size_t)b * 4096 + d;
#pragma unroll
  for (int c = 0; c < 64; c++) o[c * 64] = v[c] * inv;
}

// ---------------------------------------------------------------------------
// K3: out[b,m,d] = alpha * sum_c key_cur[b,m,c]*P[c,d] + val_cur[b,m,d].
// grid = 4*256 blocks x 256 thr; P + transposed key in LDS; 2x8/lane tile.
// ---------------------------------------------------------------------------
__global__ __launch_bounds__(256, 4) void k3_out(
    const float* __restrict__ P, const float* __restrict__ keyc,
    const float* __restrict__ valc, const float* __restrict__ alphap,
    float* __restrict__ out) {
  __shared__ float Ps[4096];
  __shared__ float kT[64 * 68];

  int bb = blockIdx.x >> 8;
  int mb = blockIdx.x & 255;
  int m0 = mb * 64;
  int t = threadIdx.x;

  const float4* p4 = (const float4*)(P + (size_t)bb * 4096);
  float4* ps4 = (float4*)Ps;
#pragma unroll
  for (int u = 0; u < 4; u++) ps4[t + 256 * u] = p4[t + 256 * u];

  int r  = t >> 2;
  int cb = (t & 3) * 16;
  const float* krow = keyc + ((size_t)bb * N_TOK + m0 + r) * 64;
#pragma unroll
  for (int u = 0; u < 4; u++) {
    float4 kk = *(const float4*)&krow[cb + 4 * u];
    int c = cb + 4 * u;
    kT[(c + 0) * 68 + r] = kk.x;
    kT[(c + 1) * 68 + r] = kk.y;
    kT[(c + 2) * 68 + r] = kk.z;
    kT[(c + 3) * 68 + r] = kk.w;
  }
  __syncthreads();

  int wave = t >> 6, lane = t & 63;
  int mi = lane >> 3, j = lane & 7;
  int m = wave * 16 + mi * 2;

  float acc[2][8];
#pragma unroll
  for (int a = 0; a < 2; a++)
#pragma unroll
    for (int d = 0; d < 8; d++) acc[a][d] = 0.f;

#pragma unroll 4
  for (int c = 0; c < 64; c++) {
    float2 kk = *(const float2*)&kT[c * 68 + m];
    float4 p0 = *(const float4*)&Ps[c * 64 + 8 * j];
    float4 p1 = *(const float4*)&Ps[c * 64 + 8 * j + 4];
    float pr[8] = {p0.x, p0.y, p0.z, p0.w, p1.x, p1.y, p1.z, p1.w};
#pragma unroll
    for (int d = 0; d < 8; d++) {
      acc[0][d] = fmaf(kk.x, pr[d], acc[0][d]);
      acc[1][d] = fmaf(kk.y, pr[d], acc[1][d]);
    }
  }

  float alpha = alphap[0];
#pragma unroll
  for (int a = 0; a < 2; a++) {
    size_t off = ((size_t)bb * N_TOK + m0 + m + a) * 64 + 8 * j;
    float4 v0 = *(const float4*)&valc[off];
    float4 v1 = *(const float4*)&valc[off + 4];
    float4 o0 = make_float4(fmaf(alpha, acc[a][0], v0.x),
                            fmaf(alpha, acc[a][1], v0.y),
                            fmaf(alpha, acc[a][2], v0.z),
                            fmaf(alpha, acc[a][3], v0.w));
    float4 o1 = make_float4(fmaf(alpha, acc[a][4], v1.x),
                            fmaf(alpha, acc[a][5], v1.y),
                            fmaf(alpha, acc[a][6], v1.z),
                            fmaf(alpha, acc[a][7], v1.w));
    *(float4*)&out[off] = o0;
    *(float4*)&out[off + 4] = o1;
  }
}

// ---------------------------------------------------------------------------
extern "C" void kernel_launch(void* const* d_in, const int* in_sizes, int n_in,
                              void* d_out, int out_size, void* d_ws,
                              size_t ws_size, hipStream_t stream) {
  const float* key_mem = (const float*)d_in[0];
  const float* val_mem = (const float*)d_in[1];
  const float* key_cur = (const float*)d_in[2];
  const float* val_cur = (const float*)d_in[3];
  const float* alpha   = (const float*)d_in[4];
  float* out = (float*)d_out;
  float* ws  = (float*)d_ws;

  float* part = ws;                                    // 512 tiles (8.4 MB)
  float* kv   = ws + (size_t)(N_BATCH * BPB) * 4096;   // 4 tiles
  float* P    = ws;                                    // aliases consumed part

  k1_accum<<<N_BATCH * BPB, 512, 0, stream>>>(key_mem, val_mem, part);
  k2_reduce<<<256, 256, 0, stream>>>(part, kv, BPB);
  k2b_softmax<<<N_BATCH, 64, 0, stream>>>(kv, P);
  k3_out<<<N_BATCH * (N_TOK / 64), 256, 0, stream>>>(P, key_cur, val_cur,
                                                     alpha, out);
}